// Round 12
// baseline (365.657 us; speedup 1.0000x reference)
//
#include <hip/hip_runtime.h>

#define N_NODES 32768
#define C_IN 128
#define C_W 32
#define KK 24
#define SS 5
#define GG 8                 // nodes per k_node block (one per wave)
#define AGS (KK * C_W + 4)   // padded sAgg stride

#define BF_LO(u) __uint_as_float((u) << 16)
#define BF_HI(u) __uint_as_float((u) & 0xFFFF0000u)

// ---------------- colstats(x) for BN1 + edge histogram ----------------
__global__ void __launch_bounds__(256) k_pre(
        const float* __restrict__ x, float* __restrict__ s1,
        const int* __restrict__ ei, int E, int* __restrict__ counts) {
    int t = threadIdx.x;
    int c = t % C_IN;
    int r0 = blockIdx.x * 2 + t / C_IN;
    float s = 0.f, sq = 0.f;
    for (int r = r0; r < N_NODES; r += 1024) {
        float v = x[(size_t)r * C_IN + c];
        s += v; sq += v * v;
    }
    atomicAdd(&s1[c], s);
    atomicAdd(&s1[C_IN + c], sq);
    for (int e = blockIdx.x * 256 + t; e < E; e += 512 * 256)
        atomicAdd(&counts[ei[E + e]], 1);
}

// ---------------- input MLP: lrelu(bn1(x)) @ lin1_w (+ BN2 stats) ----------------
__global__ void __launch_bounds__(256) k_mlp1(
        const float* __restrict__ x, const float* __restrict__ s1,
        const float* __restrict__ g1, const float* __restrict__ b1,
        const float* __restrict__ w1, float* __restrict__ hpre,
        float* __restrict__ s2sh) {
    __shared__ float sAB[2][C_IN];
    __shared__ float sx[32][C_IN + 4];
    __shared__ float sw[C_IN][C_W];
    const int t = threadIdx.x;
    const int row0 = blockIdx.x * 32;
    if (t < C_IN) {
        float mean = s1[t] * (1.f / N_NODES);
        float var = s1[C_IN + t] * (1.f / N_NODES) - mean * mean;
        float a = g1[t] * rsqrtf(var + 1e-5f);
        sAB[0][t] = a; sAB[1][t] = b1[t] - mean * a;
    }
    for (int idx = t; idx < C_IN * C_W; idx += 256)
        sw[idx / C_W][idx % C_W] = w1[idx];
    __syncthreads();
    for (int idx = t; idx < 32 * 32; idx += 256) {
        int r = idx >> 5, cq = idx & 31;
        float4 v = *(const float4*)&x[(size_t)(row0 + r) * C_IN + cq * 4];
        float* d = &sx[r][cq * 4];
        float a0 = sAB[0][cq*4+0]*v.x + sAB[1][cq*4+0];
        float a1 = sAB[0][cq*4+1]*v.y + sAB[1][cq*4+1];
        float a2 = sAB[0][cq*4+2]*v.z + sAB[1][cq*4+2];
        float a3 = sAB[0][cq*4+3]*v.w + sAB[1][cq*4+3];
        d[0] = a0 >= 0.f ? a0 : 0.1f * a0;
        d[1] = a1 >= 0.f ? a1 : 0.1f * a1;
        d[2] = a2 >= 0.f ? a2 : 0.1f * a2;
        d[3] = a3 >= 0.f ? a3 : 0.1f * a3;
    }
    __syncthreads();
    const int r = t >> 3, c0 = (t & 7) * 4;
    float ac0 = 0.f, ac1 = 0.f, ac2 = 0.f, ac3 = 0.f;
    #pragma unroll 8
    for (int cc = 0; cc < C_IN; ++cc) {
        float xv = sx[r][cc];
        float4 wv = *(const float4*)&sw[cc][c0];
        ac0 += xv * wv.x; ac1 += xv * wv.y; ac2 += xv * wv.z; ac3 += xv * wv.w;
    }
    float4 o; o.x = ac0; o.y = ac1; o.z = ac2; o.w = ac3;
    *(float4*)&hpre[(size_t)(row0 + r) * C_W + c0] = o;
    __syncthreads();
    sx[r][c0] = ac0; sx[r][c0+1] = ac1; sx[r][c0+2] = ac2; sx[r][c0+3] = ac3;
    __syncthreads();
    if (t < C_W) {
        float s = 0.f, sq = 0.f;
        #pragma unroll
        for (int rr = 0; rr < 32; ++rr) {
            float v = sx[rr][t];
            s += v; sq += v * v;
        }
        int sh = (blockIdx.x & 7) * 64;
        atomicAdd(&s2sh[sh + t], s);
        atomicAdd(&s2sh[sh + C_W + t], sq);
    }
}

// ---------------- single-block scan (1024 thr x 32 elems, int4) ----------------
__global__ void __launch_bounds__(1024) k_scan(
        const int* __restrict__ counts, int* __restrict__ offsets,
        int* __restrict__ cursor) {
    __shared__ int sblk[1024];
    const int t = threadIdx.x;
    const int base = t * 32;
    const int4* cp = (const int4*)(counts + base);
    int loc[32];
    int s = 0;
    #pragma unroll
    for (int q = 0; q < 8; ++q) {
        int4 v = cp[q];
        loc[q*4+0] = s; s += v.x;
        loc[q*4+1] = s; s += v.y;
        loc[q*4+2] = s; s += v.z;
        loc[q*4+3] = s; s += v.w;
    }
    sblk[t] = s;
    __syncthreads();
    for (int d = 1; d < 1024; d <<= 1) {
        int u = (t >= d) ? sblk[t - d] : 0;
        __syncthreads();
        sblk[t] += u;
        __syncthreads();
    }
    const int blockbase = sblk[t] - s;
    #pragma unroll
    for (int q = 0; q < 8; ++q) {
        int4 o;
        o.x = blockbase + loc[q*4+0];
        o.y = blockbase + loc[q*4+1];
        o.z = blockbase + loc[q*4+2];
        o.w = blockbase + loc[q*4+3];
        ((int4*)(offsets + base))[q] = o;
        ((int4*)(cursor + base))[q] = o;
    }
    if (t == 1023) offsets[N_NODES] = sblk[1023];
}

// ---------------- edge kernel: WeightNet + h gather/activate + bf16 CSR streams ----
__global__ void __launch_bounds__(256) k_edge(
        const int* __restrict__ ei, int E,
        const float* __restrict__ pos, const float* __restrict__ ori,
        const int* __restrict__ seq,
        const float* __restrict__ wnw, const float* __restrict__ wnb,
        const float* __restrict__ s2sh, const float* __restrict__ g2,
        const float* __restrict__ b2, const float* __restrict__ hpre,
        int* __restrict__ cursor,
        unsigned int* __restrict__ wPerm, unsigned short* __restrict__ hPerm) {
    __shared__ float sWnw[11][169];
    __shared__ float sWnb[11][24];
    __shared__ float sA2[C_W], sB2[C_W];
    const int t = threadIdx.x;
    for (int idx = t; idx < 11 * 168; idx += 256)
        sWnw[idx / 168][idx % 168] = wnw[idx];
    for (int idx = t; idx < 11 * 24; idx += 256)
        sWnb[idx / 24][idx % 24] = wnb[idx];
    if (t < C_W) {
        float s = 0.f, sq = 0.f;
        #pragma unroll
        for (int j = 0; j < 8; ++j) {
            s  += s2sh[j * 64 + t];
            sq += s2sh[j * 64 + C_W + t];
        }
        float mean = s * (1.f / N_NODES);
        float var = sq * (1.f / N_NODES) - mean * mean;
        float a = g2[t] * rsqrtf(var + 1e-5f);
        sA2[t] = a; sB2[t] = b2[t] - mean * a;
    }
    __syncthreads();
    const int e = blockIdx.x * 256 + t;
    if (e >= E) return;
    const int src = ei[e];
    const int dst = ei[E + e];
    int ds = seq[src] - seq[dst];
    ds = ds < -SS ? -SS : (ds > SS ? SS : ds);
    const int sb = ds + SS;
    float dx = pos[src * 3 + 0] - pos[dst * 3 + 0];
    float dy = pos[src * 3 + 1] - pos[dst * 3 + 1];
    float dz = pos[src * 3 + 2] - pos[dst * 3 + 2];
    float dist = sqrtf(dx * dx + dy * dy + dz * dz);
    float inv = 1.f / (dist + 1e-9f);
    float ux = dx * inv, uy = dy * inv, uz = dz * inv;
    float b0 = ori[src * 9 + 0], b1 = ori[src * 9 + 1], b2v = ori[src * 9 + 2];
    float delta[7];
    #pragma unroll
    for (int r = 0; r < 3; ++r) {
        float m0 = ori[dst * 9 + r * 3 + 0];
        float m1 = ori[dst * 9 + r * 3 + 1];
        float m2 = ori[dst * 9 + r * 3 + 2];
        delta[r]     = m0 * ux + m1 * uy + m2 * uz;
        delta[3 + r] = m0 * b0 + m1 * b1 + m2 * b2v;
    }
    delta[6] = dist * 0.125f;
    float w[KK];
    #pragma unroll
    for (int k = 0; k < KK; ++k) {
        float acc = sWnb[sb][k];
        #pragma unroll
        for (int f = 0; f < 7; ++f)
            acc += delta[f] * sWnw[sb][f * 24 + k];
        w[k] = acc >= 0.f ? acc : 0.2f * acc;
    }
    const int p = atomicAdd(&cursor[dst], 1);
    // pack w -> bf16, 12 uints
    unsigned int pk[12];
    #pragma unroll
    for (int jj = 0; jj < 12; ++jj) {
        unsigned int ulo = __float_as_uint(w[2*jj]);
        unsigned int uhi = __float_as_uint(w[2*jj+1]);
        ulo = (ulo + 0x7FFFu + ((ulo >> 16) & 1u)) >> 16;
        uhi = (uhi + 0x7FFFu + ((uhi >> 16) & 1u)) & 0xFFFF0000u;
        pk[jj] = uhi | ulo;
    }
    {
        uint4* wp = (uint4*)(wPerm + (size_t)p * 12);
        uint4 o0; o0.x = pk[0]; o0.y = pk[1]; o0.z = pk[2]; o0.w = pk[3];
        uint4 o1; o1.x = pk[4]; o1.y = pk[5]; o1.z = pk[6]; o1.w = pk[7];
        uint4 o2; o2.x = pk[8]; o2.y = pk[9]; o2.z = pk[10]; o2.w = pk[11];
        wp[0] = o0; wp[1] = o1; wp[2] = o2;
    }
    // gather h[src], BN2 + lrelu, pack bf16, write 32 ushorts (4 uint4)
    {
        uint4* hp = (uint4*)(hPerm + (size_t)p * C_W);
        const float4* hs = (const float4*)(hpre + (size_t)src * C_W);
        #pragma unroll
        for (int g = 0; g < 4; ++g) {
            float4 v0 = hs[2*g], v1 = hs[2*g+1];
            float f[8];
            f[0]=v0.x; f[1]=v0.y; f[2]=v0.z; f[3]=v0.w;
            f[4]=v1.x; f[5]=v1.y; f[6]=v1.z; f[7]=v1.w;
            unsigned int o[4];
            #pragma unroll
            for (int j = 0; j < 4; ++j) {
                int cc = g * 8 + 2 * j * 1;  // pairs (2j,2j+1) within this group of 8
                float a0 = sA2[g*8+2*j]   * f[2*j]   + sB2[g*8+2*j];
                float a1 = sA2[g*8+2*j+1] * f[2*j+1] + sB2[g*8+2*j+1];
                a0 = a0 >= 0.f ? a0 : 0.1f * a0;
                a1 = a1 >= 0.f ? a1 : 0.1f * a1;
                unsigned int ulo = __float_as_uint(a0);
                unsigned int uhi = __float_as_uint(a1);
                ulo = (ulo + 0x7FFFu + ((ulo >> 16) & 1u)) >> 16;
                uhi = (uhi + 0x7FFFu + ((uhi >> 16) & 1u)) & 0xFFFF0000u;
                o[j] = uhi | ulo;
                (void)cc;
            }
            uint4 ov; ov.x = o[0]; ov.y = o[1]; ov.z = o[2]; ov.w = o[3];
            hp[g] = ov;
        }
    }
}

// ---------------- aggregation + conv projection (+ BN3 stats) ----------------
// 512 threads = 8 waves; one node per wave; ZERO barriers in edge loop.
// Pure-stream inputs: per 16-edge chunk, 1 LDS stage of w + 8 coalesced h loads.
__global__ void __launch_bounds__(512) k_node(
    const int* __restrict__ offsets,
    const unsigned int* __restrict__ wPerm, const unsigned short* __restrict__ hPerm,
    const float* __restrict__ convw,
    float* __restrict__ convout, float* __restrict__ s3sh) {

    __shared__ int sOff[GG + 1];
    __shared__ float sAgg[GG][AGS];
    __shared__ union SU {
        unsigned int w[GG][16 * 12];                                    // 6KB
        struct { float red[8][GG][C_W]; float rv[GG][C_W]; float rq[GG][C_W]; } fin; // 10KB
    } U;

    const int t = threadIdx.x;
    const int i0 = blockIdx.x * GG;
    if (t <= GG) sOff[t] = offsets[i0 + t];
    __syncthreads();

    const int w = t >> 6, lane = t & 63, c = lane & 31, s = lane >> 5;
    const int beg = sOff[w], end = sOff[w + 1];
    unsigned int* sWw = U.w[w];
    float a[KK];
    #pragma unroll
    for (int k = 0; k < KK; ++k) a[k] = 0.f;

    for (int cb = beg; cb < end; cb += 16) {
        const int m = min(16, end - cb);
        // stage w: m*3 uint4 (<=48), one conditional load per lane
        const uint4* gw = (const uint4*)(wPerm + (size_t)cb * 12);
        if (lane < m * 3) ((uint4*)sWw)[lane] = gw[lane];
        // h preload: 8 independent coalesced ushort loads (edge 2q+s, channel c)
        float hr[8];
        #pragma unroll
        for (int q = 0; q < 8; ++q) {
            int e = cb + 2 * q + s;
            hr[q] = (e < end)
                ? __uint_as_float(((unsigned int)hPerm[(size_t)e * C_W + c]) << 16)
                : 0.f;
        }
        #pragma unroll
        for (int q = 0; q < 8; ++q) {
            const float v = hr[q];
            const int ee = min(2 * q + s, m - 1);
            const uint4* wp = (const uint4*)&sWw[ee * 12];
            const uint4 A = wp[0], B = wp[1], Cc = wp[2];
            a[0]  += BF_LO(A.x) * v;  a[1]  += BF_HI(A.x) * v;
            a[2]  += BF_LO(A.y) * v;  a[3]  += BF_HI(A.y) * v;
            a[4]  += BF_LO(A.z) * v;  a[5]  += BF_HI(A.z) * v;
            a[6]  += BF_LO(A.w) * v;  a[7]  += BF_HI(A.w) * v;
            a[8]  += BF_LO(B.x) * v;  a[9]  += BF_HI(B.x) * v;
            a[10] += BF_LO(B.y) * v;  a[11] += BF_HI(B.y) * v;
            a[12] += BF_LO(B.z) * v;  a[13] += BF_HI(B.z) * v;
            a[14] += BF_LO(B.w) * v;  a[15] += BF_HI(B.w) * v;
            a[16] += BF_LO(Cc.x) * v; a[17] += BF_HI(Cc.x) * v;
            a[18] += BF_LO(Cc.y) * v; a[19] += BF_HI(Cc.y) * v;
            a[20] += BF_LO(Cc.z) * v; a[21] += BF_HI(Cc.z) * v;
            a[22] += BF_LO(Cc.w) * v; a[23] += BF_HI(Cc.w) * v;
        }
    }
    // fold halves (even/odd edges)
    #pragma unroll
    for (int k = 0; k < KK; ++k) a[k] += __shfl_xor(a[k], 32, 64);
    if (s == 0) {
        #pragma unroll
        for (int k = 0; k < KK; ++k) sAgg[w][k * C_W + c] = a[k];
    }
    __syncthreads();

    // projection: t = sl8*64 + gp*8 + coq ; each thread 96 rows x 4 cols
    {
        const int coq = t & 7;
        const int gp  = (t >> 3) & 7;
        const int sl8 = t >> 6;
        const int r0  = sl8 * 96;
        float4 acc; acc.x = acc.y = acc.z = acc.w = 0.f;
        #pragma unroll 6
        for (int rc = 0; rc < 96; rc += 4) {
            const float4 s4 = *(const float4*)&sAgg[gp][r0 + rc];
            const float4 w0 = *(const float4*)&convw[(size_t)(r0+rc+0)*32 + coq*4];
            const float4 w1 = *(const float4*)&convw[(size_t)(r0+rc+1)*32 + coq*4];
            const float4 w2 = *(const float4*)&convw[(size_t)(r0+rc+2)*32 + coq*4];
            const float4 w3 = *(const float4*)&convw[(size_t)(r0+rc+3)*32 + coq*4];
            acc.x += s4.x*w0.x + s4.y*w1.x + s4.z*w2.x + s4.w*w3.x;
            acc.y += s4.x*w0.y + s4.y*w1.y + s4.z*w2.y + s4.w*w3.y;
            acc.z += s4.x*w0.z + s4.y*w1.z + s4.z*w2.z + s4.w*w3.z;
            acc.w += s4.x*w0.w + s4.y*w1.w + s4.z*w2.w + s4.w*w3.w;
        }
        *(float4*)&U.fin.red[sl8][gp][coq * 4] = acc;
    }
    __syncthreads();
    if (t < 256) {
        const int gg = t >> 5, co = t & 31;
        float v = 0.f;
        #pragma unroll
        for (int sl = 0; sl < 8; ++sl) v += U.fin.red[sl][gg][co];
        convout[(size_t)(i0 + gg) * C_W + co] = v;
        U.fin.rv[gg][co] = v; U.fin.rq[gg][co] = v * v;
    }
    __syncthreads();
    if (t < 64) {
        int cc = t & 31;
        bool isq = t >= C_W;
        float s2 = 0.f;
        #pragma unroll
        for (int gg = 0; gg < GG; ++gg)
            s2 += isq ? U.fin.rq[gg][cc] : U.fin.rv[gg][cc];
        atomicAdd(&s3sh[(blockIdx.x & 7) * 64 + t], s2);
    }
}

// ---------------- output: lrelu(bn3(conv)) @ lin2_w + x (float4) ----------------
__global__ void __launch_bounds__(256) k_out(
        const float* __restrict__ conv, const float* __restrict__ s3sh,
        const float* __restrict__ g3, const float* __restrict__ b3,
        const float* __restrict__ w2, const float* __restrict__ x,
        float* __restrict__ out) {
    __shared__ float sAB[2][C_W];
    __shared__ float sh[8][C_W];
    __shared__ float sw2[C_W][C_IN];
    const int t = threadIdx.x;
    const int row0 = blockIdx.x * 8;
    if (t < C_W) {
        float s = 0.f, sq = 0.f;
        #pragma unroll
        for (int j = 0; j < 8; ++j) {
            s  += s3sh[j * 64 + t];
            sq += s3sh[j * 64 + C_W + t];
        }
        float mean = s * (1.f / N_NODES);
        float var = sq * (1.f / N_NODES) - mean * mean;
        float a = g3[t] * rsqrtf(var + 1e-5f);
        sAB[0][t] = a; sAB[1][t] = b3[t] - mean * a;
    }
    for (int idx = t; idx < C_W * C_IN; idx += 256)
        sw2[idx >> 7][idx & 127] = w2[idx];
    __syncthreads();
    {
        float v = conv[(size_t)row0 * C_W + t];
        int r = t >> 5, cc = t & 31;
        v = sAB[0][cc] * v + sAB[1][cc];
        sh[r][cc] = v >= 0.f ? v : 0.1f * v;
    }
    __syncthreads();
    const int r = t >> 5, c4 = (t & 31) * 4;
    float4 acc = *(const float4*)&x[(size_t)(row0 + r) * C_IN + c4];
    #pragma unroll 8
    for (int cw = 0; cw < C_W; ++cw) {
        float hv = sh[r][cw];
        float4 wv = *(const float4*)&sw2[cw][c4];
        acc.x += hv * wv.x; acc.y += hv * wv.y;
        acc.z += hv * wv.z; acc.w += hv * wv.w;
    }
    *(float4*)&out[(size_t)(row0 + r) * C_IN + c4] = acc;
}

extern "C" void kernel_launch(void* const* d_in, const int* in_sizes, int n_in,
                              void* d_out, int out_size, void* d_ws, size_t ws_size,
                              hipStream_t stream) {
    const float* x     = (const float*)d_in[0];
    const float* pos   = (const float*)d_in[1];
    const float* ori   = (const float*)d_in[2];
    const int*   seq   = (const int*)d_in[3];
    const int*   ei    = (const int*)d_in[4];
    const float* bn1g  = (const float*)d_in[5];
    const float* bn1b  = (const float*)d_in[6];
    const float* lin1w = (const float*)d_in[7];
    const float* bn2g  = (const float*)d_in[8];
    const float* bn2b  = (const float*)d_in[9];
    const float* wnw   = (const float*)d_in[10];
    const float* wnb   = (const float*)d_in[11];
    const float* convw = (const float*)d_in[12];
    const float* bn3g  = (const float*)d_in[13];
    const float* bn3b  = (const float*)d_in[14];
    const float* lin2w = (const float*)d_in[15];
    float* out = (float*)d_out;
    const int E = in_sizes[4] / 2;

    char* wsb = (char*)d_ws;
    size_t off = 0;
    auto alloc = [&](size_t bytes) {
        void* p = wsb + off;
        off = (off + bytes + 255) & ~(size_t)255;
        return p;
    };
    float* s1      = (float*)alloc(256 * 4);
    float* s2sh    = (float*)alloc(512 * 4);
    float* s3sh    = (float*)alloc(512 * 4);
    int*   counts  = (int*)alloc((size_t)N_NODES * 4);
    size_t zero_bytes = off;
    int*   offsets = (int*)alloc(((size_t)N_NODES + 1) * 4);
    int*   cursor  = (int*)alloc((size_t)N_NODES * 4);
    float* hpre    = (float*)alloc((size_t)N_NODES * C_W * 4);
    float* convo   = (float*)alloc((size_t)N_NODES * C_W * 4);
    unsigned int*   wPerm = (unsigned int*)alloc((size_t)E * 12 * 4);
    unsigned short* hPerm = (unsigned short*)alloc((size_t)E * C_W * 2);

    hipMemsetAsync(wsb, 0, zero_bytes, stream);

    k_pre<<<512, 256, 0, stream>>>(x, s1, ei, E, counts);
    k_scan<<<1, 1024, 0, stream>>>(counts, offsets, cursor);
    k_mlp1<<<N_NODES / 32, 256, 0, stream>>>(x, s1, bn1g, bn1b, lin1w, hpre, s2sh);
    k_edge<<<(E + 255) / 256, 256, 0, stream>>>(ei, E, pos, ori, seq, wnw, wnb,
                                                s2sh, bn2g, bn2b, hpre, cursor,
                                                wPerm, hPerm);
    k_node<<<N_NODES / GG, 512, 0, stream>>>(offsets, wPerm, hPerm, convw,
                                             convo, s3sh);
    k_out<<<N_NODES / 8, 256, 0, stream>>>(convo, s3sh, bn3g, bn3b, lin2w, x, out);
}

// Round 13
// 284.621 us; speedup vs baseline: 1.2847x; 1.2847x over previous
//
#include <hip/hip_runtime.h>

#define N_NODES 32768
#define C_IN 128
#define C_W 32
#define KK 24
#define SS 5
#define NPB 4                // nodes per mega-block (one per wave)
#define TC 256               // tranche capacity (edges)
#define AGS (KK * C_W + 4)   // padded sAgg stride
#define WNS 172              // padded weightnet W stride
#define WBS 28               // padded weightnet bias stride
#define HS 36                // sH row stride (ushorts) -> 72B, conflict-free

#define BF_LO(u) __uint_as_float((u) << 16)
#define BF_HI(u) __uint_as_float((u) & 0xFFFF0000u)

__device__ __forceinline__ unsigned int bf16pair(float lo, float hi) {
    unsigned int ulo = __float_as_uint(lo);
    unsigned int uhi = __float_as_uint(hi);
    ulo = (ulo + 0x7FFFu + ((ulo >> 16) & 1u)) >> 16;
    uhi = (uhi + 0x7FFFu + ((uhi >> 16) & 1u)) & 0xFFFF0000u;
    return uhi | ulo;
}

// ---------------- colstats(x) for BN1 + edge histogram ----------------
__global__ void __launch_bounds__(256) k_pre(
        const float* __restrict__ x, float* __restrict__ s1,
        const int* __restrict__ ei, int E, int* __restrict__ counts) {
    int t = threadIdx.x;
    int c = t % C_IN;
    int r0 = blockIdx.x * 2 + t / C_IN;
    float s = 0.f, sq = 0.f;
    for (int r = r0; r < N_NODES; r += 1024) {
        float v = x[(size_t)r * C_IN + c];
        s += v; sq += v * v;
    }
    atomicAdd(&s1[c], s);
    atomicAdd(&s1[C_IN + c], sq);
    for (int e = blockIdx.x * 256 + t; e < E; e += 512 * 256)
        atomicAdd(&counts[ei[E + e]], 1);
}

// ---------------- input MLP: lrelu(bn1(x)) @ lin1_w (+ BN2 stats) ----------------
__global__ void __launch_bounds__(256) k_mlp1(
        const float* __restrict__ x, const float* __restrict__ s1,
        const float* __restrict__ g1, const float* __restrict__ b1,
        const float* __restrict__ w1, float* __restrict__ hpre,
        float* __restrict__ s2sh) {
    __shared__ float sAB[2][C_IN];
    __shared__ float sx[32][C_IN + 4];
    __shared__ float sw[C_IN][C_W];
    const int t = threadIdx.x;
    const int row0 = blockIdx.x * 32;
    if (t < C_IN) {
        float mean = s1[t] * (1.f / N_NODES);
        float var = s1[C_IN + t] * (1.f / N_NODES) - mean * mean;
        float a = g1[t] * rsqrtf(var + 1e-5f);
        sAB[0][t] = a; sAB[1][t] = b1[t] - mean * a;
    }
    for (int idx = t; idx < C_IN * C_W; idx += 256)
        sw[idx / C_W][idx % C_W] = w1[idx];
    __syncthreads();
    for (int idx = t; idx < 32 * 32; idx += 256) {
        int r = idx >> 5, cq = idx & 31;
        float4 v = *(const float4*)&x[(size_t)(row0 + r) * C_IN + cq * 4];
        float* d = &sx[r][cq * 4];
        float a0 = sAB[0][cq*4+0]*v.x + sAB[1][cq*4+0];
        float a1 = sAB[0][cq*4+1]*v.y + sAB[1][cq*4+1];
        float a2 = sAB[0][cq*4+2]*v.z + sAB[1][cq*4+2];
        float a3 = sAB[0][cq*4+3]*v.w + sAB[1][cq*4+3];
        d[0] = a0 >= 0.f ? a0 : 0.1f * a0;
        d[1] = a1 >= 0.f ? a1 : 0.1f * a1;
        d[2] = a2 >= 0.f ? a2 : 0.1f * a2;
        d[3] = a3 >= 0.f ? a3 : 0.1f * a3;
    }
    __syncthreads();
    const int r = t >> 3, c0 = (t & 7) * 4;
    float ac0 = 0.f, ac1 = 0.f, ac2 = 0.f, ac3 = 0.f;
    #pragma unroll 8
    for (int cc = 0; cc < C_IN; ++cc) {
        float xv = sx[r][cc];
        float4 wv = *(const float4*)&sw[cc][c0];
        ac0 += xv * wv.x; ac1 += xv * wv.y; ac2 += xv * wv.z; ac3 += xv * wv.w;
    }
    float4 o; o.x = ac0; o.y = ac1; o.z = ac2; o.w = ac3;
    *(float4*)&hpre[(size_t)(row0 + r) * C_W + c0] = o;
    __syncthreads();
    sx[r][c0] = ac0; sx[r][c0+1] = ac1; sx[r][c0+2] = ac2; sx[r][c0+3] = ac3;
    __syncthreads();
    if (t < C_W) {
        float s = 0.f, sq = 0.f;
        #pragma unroll
        for (int rr = 0; rr < 32; ++rr) {
            float v = sx[rr][t];
            s += v; sq += v * v;
        }
        int sh = (blockIdx.x & 7) * 64;
        atomicAdd(&s2sh[sh + t], s);
        atomicAdd(&s2sh[sh + C_W + t], sq);
    }
}

// ---------------- single-block scan (1024 thr x 32 elems, int4) ----------------
__global__ void __launch_bounds__(1024) k_scan(
        const int* __restrict__ counts, int* __restrict__ offsets,
        int* __restrict__ cursor) {
    __shared__ int sblk[1024];
    const int t = threadIdx.x;
    const int base = t * 32;
    const int4* cp = (const int4*)(counts + base);
    int loc[32];
    int s = 0;
    #pragma unroll
    for (int q = 0; q < 8; ++q) {
        int4 v = cp[q];
        loc[q*4+0] = s; s += v.x;
        loc[q*4+1] = s; s += v.y;
        loc[q*4+2] = s; s += v.z;
        loc[q*4+3] = s; s += v.w;
    }
    sblk[t] = s;
    __syncthreads();
    for (int d = 1; d < 1024; d <<= 1) {
        int u = (t >= d) ? sblk[t - d] : 0;
        __syncthreads();
        sblk[t] += u;
        __syncthreads();
    }
    const int blockbase = sblk[t] - s;
    #pragma unroll
    for (int q = 0; q < 8; ++q) {
        int4 o;
        o.x = blockbase + loc[q*4+0];
        o.y = blockbase + loc[q*4+1];
        o.z = blockbase + loc[q*4+2];
        o.w = blockbase + loc[q*4+3];
        ((int4*)(offsets + base))[q] = o;
        ((int4*)(cursor + base))[q] = o;
    }
    if (t == 1023) offsets[N_NODES] = sblk[1023];
}

// ---------------- scatter: CSR permutation of src indices ----------------
__global__ void __launch_bounds__(256) k_scatter(
        const int* __restrict__ ei, int E, int* __restrict__ cursor,
        int* __restrict__ srcPerm) {
    int e = blockIdx.x * 256 + threadIdx.x;
    if (e < E) {
        int dst = ei[E + e];
        int p = atomicAdd(&cursor[dst], 1);
        srcPerm[p] = ei[e];
    }
}

// ---------------- mega kernel: WeightNet + h + aggregation + projection ----------
// 256 threads = 4 waves = 4 nodes. Per tranche: phase A edge-parallel compute
// into LDS (bf16), phase B per-wave LDS-only accumulate. Then projection.
__global__ void __launch_bounds__(256) k_mega(
    const int* __restrict__ offsets, const int* __restrict__ srcPerm,
    const float* __restrict__ pos, const float* __restrict__ ori,
    const int* __restrict__ seq, const float* __restrict__ hpre,
    const float* __restrict__ s2sh, const float* __restrict__ g2,
    const float* __restrict__ b2,
    const float* __restrict__ wnw, const float* __restrict__ wnb,
    const float* __restrict__ convw,
    float* __restrict__ convout, float* __restrict__ s3sh) {

    __shared__ float sWnw[11 * WNS];
    __shared__ float sWnb[11 * WBS];
    __shared__ float sA2[C_W], sB2[C_W];
    __shared__ int   sOff[NPB + 1];
    __shared__ float sNd[NPB][13];     // pos[3], ori[9], seq-bits
    __shared__ union SU {
        struct { unsigned short h[TC * HS]; unsigned int w[TC * 12]; } stg;  // 30KB
        struct { float agg[NPB][AGS]; float red[8][NPB][C_W];
                 float rv[NPB][C_W]; float rq[NPB][C_W]; } fin;              // 18KB
    } U;

    const int t = threadIdx.x;
    const int i0 = blockIdx.x * NPB;
    for (int idx = t; idx < 11 * 168; idx += 256)
        sWnw[(idx / 168) * WNS + idx % 168] = wnw[idx];
    for (int idx = t; idx < 11 * 24; idx += 256)
        sWnb[(idx / 24) * WBS + idx % 24] = wnb[idx];
    if (t < C_W) {
        float s = 0.f, sq = 0.f;
        #pragma unroll
        for (int j = 0; j < 8; ++j) {
            s  += s2sh[j * 64 + t];
            sq += s2sh[j * 64 + C_W + t];
        }
        float mean = s * (1.f / N_NODES);
        float var = sq * (1.f / N_NODES) - mean * mean;
        float a = g2[t] * rsqrtf(var + 1e-5f);
        sA2[t] = a; sB2[t] = b2[t] - mean * a;
    }
    if (t <= NPB) sOff[t] = offsets[i0 + t];
    if (t < NPB * 13) {
        int n = t / 13, f = t % 13;
        float v;
        if (f < 3)       v = pos[(i0 + n) * 3 + f];
        else if (f < 12) v = ori[(i0 + n) * 9 + (f - 3)];
        else             v = __int_as_float(seq[i0 + n]);
        sNd[n][f] = v;
    }
    __syncthreads();

    const int w = t >> 6, lane = t & 63, c = lane & 31, s = lane >> 5;
    const int beg = sOff[w], end = sOff[w + 1];
    const int blkBeg = sOff[0], blkEnd = sOff[NPB];
    float a[KK];
    #pragma unroll
    for (int k = 0; k < KK; ++k) a[k] = 0.f;

    for (int base = blkBeg; base < blkEnd; base += TC) {
        const int cnt = min(TC, blkEnd - base);
        __syncthreads();   // previous tranche's LDS fully consumed
        if (t < cnt) {
            const int slot = base + t;
            const int g = (slot >= sOff[1]) + (slot >= sOff[2]) + (slot >= sOff[3]);
            const int src = srcPerm[slot];
            // ---- delta ----
            float px = pos[src*3+0], py = pos[src*3+1], pz = pos[src*3+2];
            float o0 = ori[src*9+0], o1 = ori[src*9+1], o2 = ori[src*9+2];
            int sqs = seq[src];
            float dx = px - sNd[g][0], dy = py - sNd[g][1], dz = pz - sNd[g][2];
            float dist = sqrtf(dx*dx + dy*dy + dz*dz);
            float inv = 1.f / (dist + 1e-9f);
            float ux = dx*inv, uy = dy*inv, uz = dz*inv;
            float df[7];
            #pragma unroll
            for (int r = 0; r < 3; ++r) {
                float m0 = sNd[g][3 + r*3 + 0];
                float m1 = sNd[g][3 + r*3 + 1];
                float m2 = sNd[g][3 + r*3 + 2];
                df[r]     = m0*ux + m1*uy + m2*uz;
                df[3 + r] = m0*o0 + m1*o1 + m2*o2;
            }
            df[6] = dist * 0.125f;
            int dsq = sqs - __float_as_int(sNd[g][12]);
            dsq = dsq < -SS ? -SS : (dsq > SS ? SS : dsq);
            const int sb = dsq + SS;
            // ---- WeightNet ----
            float wv[KK];
            #pragma unroll
            for (int k = 0; k < KK; ++k) wv[k] = sWnb[sb * WBS + k];
            #pragma unroll
            for (int f = 0; f < 7; ++f) {
                float d_ = df[f];
                #pragma unroll
                for (int k = 0; k < KK; ++k)
                    wv[k] += d_ * sWnw[sb * WNS + f * 24 + k];
            }
            #pragma unroll
            for (int k = 0; k < KK; ++k) wv[k] = wv[k] >= 0.f ? wv[k] : 0.2f * wv[k];
            #pragma unroll
            for (int jj = 0; jj < 12; ++jj)
                U.stg.w[t * 12 + jj] = bf16pair(wv[2*jj], wv[2*jj+1]);
            // ---- h row: gather, BN2+lrelu, bf16 pack ----
            const float4* hs = (const float4*)(hpre + (size_t)src * C_W);
            uint2* hd = (uint2*)&U.stg.h[t * HS];
            #pragma unroll
            for (int g4 = 0; g4 < 4; ++g4) {
                float4 v0 = hs[2*g4], v1 = hs[2*g4+1];
                float f[8] = {v0.x, v0.y, v0.z, v0.w, v1.x, v1.y, v1.z, v1.w};
                #pragma unroll
                for (int j = 0; j < 8; ++j) {
                    int ch = g4 * 8 + j;
                    float av = sA2[ch] * f[j] + sB2[ch];
                    f[j] = av >= 0.f ? av : 0.1f * av;
                }
                uint2 p0; p0.x = bf16pair(f[0], f[1]); p0.y = bf16pair(f[2], f[3]);
                uint2 p1; p1.x = bf16pair(f[4], f[5]); p1.y = bf16pair(f[6], f[7]);
                hd[2*g4] = p0; hd[2*g4+1] = p1;
            }
        }
        __syncthreads();
        // ---- phase B: per-wave LDS-only accumulate ----
        const int lo = max(beg, base), hi = min(end, base + cnt);
        #pragma unroll 2
        for (int p = lo + s; p < hi; p += 2) {
            const int pr = p - base;
            const float v = BF_LO((unsigned int)U.stg.h[pr * HS + c]);
            const uint4* wp = (const uint4*)&U.stg.w[pr * 12];
            const uint4 A = wp[0], B = wp[1], Cc = wp[2];
            a[0]  += BF_LO(A.x) * v;  a[1]  += BF_HI(A.x) * v;
            a[2]  += BF_LO(A.y) * v;  a[3]  += BF_HI(A.y) * v;
            a[4]  += BF_LO(A.z) * v;  a[5]  += BF_HI(A.z) * v;
            a[6]  += BF_LO(A.w) * v;  a[7]  += BF_HI(A.w) * v;
            a[8]  += BF_LO(B.x) * v;  a[9]  += BF_HI(B.x) * v;
            a[10] += BF_LO(B.y) * v;  a[11] += BF_HI(B.y) * v;
            a[12] += BF_LO(B.z) * v;  a[13] += BF_HI(B.z) * v;
            a[14] += BF_LO(B.w) * v;  a[15] += BF_HI(B.w) * v;
            a[16] += BF_LO(Cc.x) * v; a[17] += BF_HI(Cc.x) * v;
            a[18] += BF_LO(Cc.y) * v; a[19] += BF_HI(Cc.y) * v;
            a[20] += BF_LO(Cc.z) * v; a[21] += BF_HI(Cc.z) * v;
            a[22] += BF_LO(Cc.w) * v; a[23] += BF_HI(Cc.w) * v;
        }
    }
    __syncthreads();   // staging dead; safe to overlay fin
    #pragma unroll
    for (int k = 0; k < KK; ++k) a[k] += __shfl_xor(a[k], 32, 64);
    if (s == 0) {
        #pragma unroll
        for (int k = 0; k < KK; ++k) U.fin.agg[w][k * C_W + c] = a[k];
    }
    __syncthreads();

    // projection: t = sl(8) * 32 + gp(4) * 8 + coq(8); 96 rows x 4 cols each
    {
        const int coq = t & 7;
        const int gp  = (t >> 3) & 3;
        const int sl  = t >> 5;
        const int r0  = sl * 96;
        float4 acc; acc.x = acc.y = acc.z = acc.w = 0.f;
        #pragma unroll 6
        for (int rc = 0; rc < 96; rc += 4) {
            const float4 s4 = *(const float4*)&U.fin.agg[gp][r0 + rc];
            const float4 w0 = *(const float4*)&convw[(size_t)(r0+rc+0)*32 + coq*4];
            const float4 w1 = *(const float4*)&convw[(size_t)(r0+rc+1)*32 + coq*4];
            const float4 w2 = *(const float4*)&convw[(size_t)(r0+rc+2)*32 + coq*4];
            const float4 w3 = *(const float4*)&convw[(size_t)(r0+rc+3)*32 + coq*4];
            acc.x += s4.x*w0.x + s4.y*w1.x + s4.z*w2.x + s4.w*w3.x;
            acc.y += s4.x*w0.y + s4.y*w1.y + s4.z*w2.y + s4.w*w3.y;
            acc.z += s4.x*w0.z + s4.y*w1.z + s4.z*w2.z + s4.w*w3.z;
            acc.w += s4.x*w0.w + s4.y*w1.w + s4.z*w2.w + s4.w*w3.w;
        }
        *(float4*)&U.fin.red[sl][gp][coq * 4] = acc;
    }
    __syncthreads();
    if (t < 128) {
        const int gg = t >> 5, co = t & 31;
        float v = 0.f;
        #pragma unroll
        for (int sl = 0; sl < 8; ++sl) v += U.fin.red[sl][gg][co];
        convout[(size_t)(i0 + gg) * C_W + co] = v;
        U.fin.rv[gg][co] = v; U.fin.rq[gg][co] = v * v;
    }
    __syncthreads();
    if (t < 64) {
        int cc = t & 31;
        bool isq = t >= C_W;
        float s2 = 0.f;
        #pragma unroll
        for (int gg = 0; gg < NPB; ++gg)
            s2 += isq ? U.fin.rq[gg][cc] : U.fin.rv[gg][cc];
        atomicAdd(&s3sh[(blockIdx.x & 7) * 64 + t], s2);
    }
}

// ---------------- output: lrelu(bn3(conv)) @ lin2_w + x (float4) ----------------
__global__ void __launch_bounds__(256) k_out(
        const float* __restrict__ conv, const float* __restrict__ s3sh,
        const float* __restrict__ g3, const float* __restrict__ b3,
        const float* __restrict__ w2, const float* __restrict__ x,
        float* __restrict__ out) {
    __shared__ float sAB[2][C_W];
    __shared__ float sh[8][C_W];
    __shared__ float sw2[C_W][C_IN];
    const int t = threadIdx.x;
    const int row0 = blockIdx.x * 8;
    if (t < C_W) {
        float s = 0.f, sq = 0.f;
        #pragma unroll
        for (int j = 0; j < 8; ++j) {
            s  += s3sh[j * 64 + t];
            sq += s3sh[j * 64 + C_W + t];
        }
        float mean = s * (1.f / N_NODES);
        float var = sq * (1.f / N_NODES) - mean * mean;
        float a = g3[t] * rsqrtf(var + 1e-5f);
        sAB[0][t] = a; sAB[1][t] = b3[t] - mean * a;
    }
    for (int idx = t; idx < C_W * C_IN; idx += 256)
        sw2[idx >> 7][idx & 127] = w2[idx];
    __syncthreads();
    {
        float v = conv[(size_t)row0 * C_W + t];
        int r = t >> 5, cc = t & 31;
        v = sAB[0][cc] * v + sAB[1][cc];
        sh[r][cc] = v >= 0.f ? v : 0.1f * v;
    }
    __syncthreads();
    const int r = t >> 5, c4 = (t & 31) * 4;
    float4 acc = *(const float4*)&x[(size_t)(row0 + r) * C_IN + c4];
    #pragma unroll 8
    for (int cw = 0; cw < C_W; ++cw) {
        float hv = sh[r][cw];
        float4 wv = *(const float4*)&sw2[cw][c4];
        acc.x += hv * wv.x; acc.y += hv * wv.y;
        acc.z += hv * wv.z; acc.w += hv * wv.w;
    }
    *(float4*)&out[(size_t)(row0 + r) * C_IN + c4] = acc;
}

extern "C" void kernel_launch(void* const* d_in, const int* in_sizes, int n_in,
                              void* d_out, int out_size, void* d_ws, size_t ws_size,
                              hipStream_t stream) {
    const float* x     = (const float*)d_in[0];
    const float* pos   = (const float*)d_in[1];
    const float* ori   = (const float*)d_in[2];
    const int*   seq   = (const int*)d_in[3];
    const int*   ei    = (const int*)d_in[4];
    const float* bn1g  = (const float*)d_in[5];
    const float* bn1b  = (const float*)d_in[6];
    const float* lin1w = (const float*)d_in[7];
    const float* bn2g  = (const float*)d_in[8];
    const float* bn2b  = (const float*)d_in[9];
    const float* wnw   = (const float*)d_in[10];
    const float* wnb   = (const float*)d_in[11];
    const float* convw = (const float*)d_in[12];
    const float* bn3g  = (const float*)d_in[13];
    const float* bn3b  = (const float*)d_in[14];
    const float* lin2w = (const float*)d_in[15];
    float* out = (float*)d_out;
    const int E = in_sizes[4] / 2;

    char* wsb = (char*)d_ws;
    size_t off = 0;
    auto alloc = [&](size_t bytes) {
        void* p = wsb + off;
        off = (off + bytes + 255) & ~(size_t)255;
        return p;
    };
    float* s1      = (float*)alloc(256 * 4);
    float* s2sh    = (float*)alloc(512 * 4);
    float* s3sh    = (float*)alloc(512 * 4);
    int*   counts  = (int*)alloc((size_t)N_NODES * 4);
    size_t zero_bytes = off;
    int*   offsets = (int*)alloc(((size_t)N_NODES + 1) * 4);
    int*   cursor  = (int*)alloc((size_t)N_NODES * 4);
    int*   srcPerm = (int*)alloc((size_t)E * 4);
    float* hpre    = (float*)alloc((size_t)N_NODES * C_W * 4);
    float* convo   = (float*)alloc((size_t)N_NODES * C_W * 4);

    hipMemsetAsync(wsb, 0, zero_bytes, stream);

    k_pre<<<512, 256, 0, stream>>>(x, s1, ei, E, counts);
    k_scan<<<1, 1024, 0, stream>>>(counts, offsets, cursor);
    k_scatter<<<(E + 255) / 256, 256, 0, stream>>>(ei, E, cursor, srcPerm);
    k_mlp1<<<N_NODES / 32, 256, 0, stream>>>(x, s1, bn1g, bn1b, lin1w, hpre, s2sh);
    k_mega<<<N_NODES / NPB, 256, 0, stream>>>(offsets, srcPerm, pos, ori, seq,
                                              hpre, s2sh, bn2g, bn2b, wnw, wnb,
                                              convw, convo, s3sh);
    k_out<<<N_NODES / 8, 256, 0, stream>>>(convo, s3sh, bn3g, bn3b, lin2w, x, out);
}

// Round 14
// 265.828 us; speedup vs baseline: 1.3755x; 1.0707x over previous
//
#include <hip/hip_runtime.h>

#define N_NODES 32768
#define C_IN 128
#define C_W 32
#define KK 24
#define SS 5
#define NPB 8                // nodes per mega-block (one per wave)
#define TC 256               // tranche capacity (edges)
#define AGS (KK * C_W + 4)   // padded sAgg stride
#define WNS 172              // padded weightnet W stride
#define WBS 28               // padded weightnet bias stride
#define HS 36                // sH row stride (ushorts) -> 72B

#define BF_LO(u) __uint_as_float((u) << 16)
#define BF_HI(u) __uint_as_float((u) & 0xFFFF0000u)

__device__ __forceinline__ unsigned int bf16pair(float lo, float hi) {
    unsigned int ulo = __float_as_uint(lo);
    unsigned int uhi = __float_as_uint(hi);
    ulo = (ulo + 0x7FFFu + ((ulo >> 16) & 1u)) >> 16;
    uhi = (uhi + 0x7FFFu + ((uhi >> 16) & 1u)) & 0xFFFF0000u;
    return uhi | ulo;
}

// ---------------- colstats(x) for BN1 + edge histogram ----------------
__global__ void __launch_bounds__(256) k_pre(
        const float* __restrict__ x, float* __restrict__ s1,
        const int* __restrict__ ei, int E, int* __restrict__ counts) {
    int t = threadIdx.x;
    int c = t % C_IN;
    int r0 = blockIdx.x * 2 + t / C_IN;
    float s = 0.f, sq = 0.f;
    for (int r = r0; r < N_NODES; r += 1024) {
        float v = x[(size_t)r * C_IN + c];
        s += v; sq += v * v;
    }
    atomicAdd(&s1[c], s);
    atomicAdd(&s1[C_IN + c], sq);
    for (int e = blockIdx.x * 256 + t; e < E; e += 512 * 256)
        atomicAdd(&counts[ei[E + e]], 1);
}

// ---------------- input MLP: lrelu(bn1(x)) @ lin1_w (+ BN2 stats) ----------------
__global__ void __launch_bounds__(256) k_mlp1(
        const float* __restrict__ x, const float* __restrict__ s1,
        const float* __restrict__ g1, const float* __restrict__ b1,
        const float* __restrict__ w1, float* __restrict__ hpre,
        float* __restrict__ s2sh) {
    __shared__ float sAB[2][C_IN];
    __shared__ float sx[32][C_IN + 4];
    __shared__ float sw[C_IN][C_W];
    const int t = threadIdx.x;
    const int row0 = blockIdx.x * 32;
    if (t < C_IN) {
        float mean = s1[t] * (1.f / N_NODES);
        float var = s1[C_IN + t] * (1.f / N_NODES) - mean * mean;
        float a = g1[t] * rsqrtf(var + 1e-5f);
        sAB[0][t] = a; sAB[1][t] = b1[t] - mean * a;
    }
    for (int idx = t; idx < C_IN * C_W; idx += 256)
        sw[idx / C_W][idx % C_W] = w1[idx];
    __syncthreads();
    for (int idx = t; idx < 32 * 32; idx += 256) {
        int r = idx >> 5, cq = idx & 31;
        float4 v = *(const float4*)&x[(size_t)(row0 + r) * C_IN + cq * 4];
        float* d = &sx[r][cq * 4];
        float a0 = sAB[0][cq*4+0]*v.x + sAB[1][cq*4+0];
        float a1 = sAB[0][cq*4+1]*v.y + sAB[1][cq*4+1];
        float a2 = sAB[0][cq*4+2]*v.z + sAB[1][cq*4+2];
        float a3 = sAB[0][cq*4+3]*v.w + sAB[1][cq*4+3];
        d[0] = a0 >= 0.f ? a0 : 0.1f * a0;
        d[1] = a1 >= 0.f ? a1 : 0.1f * a1;
        d[2] = a2 >= 0.f ? a2 : 0.1f * a2;
        d[3] = a3 >= 0.f ? a3 : 0.1f * a3;
    }
    __syncthreads();
    const int r = t >> 3, c0 = (t & 7) * 4;
    float ac0 = 0.f, ac1 = 0.f, ac2 = 0.f, ac3 = 0.f;
    #pragma unroll 8
    for (int cc = 0; cc < C_IN; ++cc) {
        float xv = sx[r][cc];
        float4 wv = *(const float4*)&sw[cc][c0];
        ac0 += xv * wv.x; ac1 += xv * wv.y; ac2 += xv * wv.z; ac3 += xv * wv.w;
    }
    float4 o; o.x = ac0; o.y = ac1; o.z = ac2; o.w = ac3;
    *(float4*)&hpre[(size_t)(row0 + r) * C_W + c0] = o;
    __syncthreads();
    sx[r][c0] = ac0; sx[r][c0+1] = ac1; sx[r][c0+2] = ac2; sx[r][c0+3] = ac3;
    __syncthreads();
    if (t < C_W) {
        float s = 0.f, sq = 0.f;
        #pragma unroll
        for (int rr = 0; rr < 32; ++rr) {
            float v = sx[rr][t];
            s += v; sq += v * v;
        }
        int sh = (blockIdx.x & 7) * 64;
        atomicAdd(&s2sh[sh + t], s);
        atomicAdd(&s2sh[sh + C_W + t], sq);
    }
}

// ---------------- single-block scan (1024 thr x 32 elems, int4) ----------------
__global__ void __launch_bounds__(1024) k_scan(
        const int* __restrict__ counts, int* __restrict__ offsets,
        int* __restrict__ cursor) {
    __shared__ int sblk[1024];
    const int t = threadIdx.x;
    const int base = t * 32;
    const int4* cp = (const int4*)(counts + base);
    int loc[32];
    int s = 0;
    #pragma unroll
    for (int q = 0; q < 8; ++q) {
        int4 v = cp[q];
        loc[q*4+0] = s; s += v.x;
        loc[q*4+1] = s; s += v.y;
        loc[q*4+2] = s; s += v.z;
        loc[q*4+3] = s; s += v.w;
    }
    sblk[t] = s;
    __syncthreads();
    for (int d = 1; d < 1024; d <<= 1) {
        int u = (t >= d) ? sblk[t - d] : 0;
        __syncthreads();
        sblk[t] += u;
        __syncthreads();
    }
    const int blockbase = sblk[t] - s;
    #pragma unroll
    for (int q = 0; q < 8; ++q) {
        int4 o;
        o.x = blockbase + loc[q*4+0];
        o.y = blockbase + loc[q*4+1];
        o.z = blockbase + loc[q*4+2];
        o.w = blockbase + loc[q*4+3];
        ((int4*)(offsets + base))[q] = o;
        ((int4*)(cursor + base))[q] = o;
    }
    if (t == 1023) offsets[N_NODES] = sblk[1023];
}

// ---------------- scatter: CSR permutation of src indices ----------------
__global__ void __launch_bounds__(256) k_scatter(
        const int* __restrict__ ei, int E, int* __restrict__ cursor,
        int* __restrict__ srcPerm) {
    int e = blockIdx.x * 256 + threadIdx.x;
    if (e < E) {
        int dst = ei[E + e];
        int p = atomicAdd(&cursor[dst], 1);
        srcPerm[p] = ei[e];
    }
}

// ---------------- mega kernel: WeightNet + h + aggregation + projection ----------
// 512 threads = 8 waves = 8 nodes. Phase A: 2 threads/edge (k-half, ch-half)
// compute WeightNet + activated h into LDS (bf16). Phase B: per-wave LDS-only.
__global__ void __launch_bounds__(512) k_mega(
    const int* __restrict__ offsets, const int* __restrict__ srcPerm,
    const float* __restrict__ pos, const float* __restrict__ ori,
    const int* __restrict__ seq, const float* __restrict__ hpre,
    const float* __restrict__ s2sh, const float* __restrict__ g2,
    const float* __restrict__ b2,
    const float* __restrict__ wnw, const float* __restrict__ wnb,
    const float* __restrict__ convw,
    float* __restrict__ convout, float* __restrict__ s3sh) {

    __shared__ float sWnw[11 * WNS];
    __shared__ float sWnb[11 * WBS];
    __shared__ float sA2[C_W], sB2[C_W];
    __shared__ int   sOff[NPB + 1];
    __shared__ float sNd[NPB][13];     // pos[3], ori[9], seq-bits
    __shared__ union SU {
        struct { unsigned short h[TC * HS]; unsigned int w[TC * 12]; } stg;  // 30KB
        struct { float agg[NPB][AGS]; float red[8][NPB][C_W];
                 float rv[NPB][C_W]; float rq[NPB][C_W]; } fin;              // 35KB
    } U;

    const int t = threadIdx.x;
    const int i0 = blockIdx.x * NPB;
    for (int idx = t; idx < 11 * 168; idx += 512)
        sWnw[(idx / 168) * WNS + idx % 168] = wnw[idx];
    for (int idx = t; idx < 11 * 24; idx += 512)
        sWnb[(idx / 24) * WBS + idx % 24] = wnb[idx];
    if (t < C_W) {
        float s = 0.f, sq = 0.f;
        #pragma unroll
        for (int j = 0; j < 8; ++j) {
            s  += s2sh[j * 64 + t];
            sq += s2sh[j * 64 + C_W + t];
        }
        float mean = s * (1.f / N_NODES);
        float var = sq * (1.f / N_NODES) - mean * mean;
        float a = g2[t] * rsqrtf(var + 1e-5f);
        sA2[t] = a; sB2[t] = b2[t] - mean * a;
    }
    if (t <= NPB) sOff[t] = offsets[i0 + t];
    if (t < NPB * 13) {
        int n = t / 13, f = t % 13;
        float v;
        if (f < 3)       v = pos[(i0 + n) * 3 + f];
        else if (f < 12) v = ori[(i0 + n) * 9 + (f - 3)];
        else             v = __int_as_float(seq[i0 + n]);
        sNd[n][f] = v;
    }
    __syncthreads();

    const int w = t >> 6, lane = t & 63, c = lane & 31, s = lane >> 5;
    const int beg = sOff[w], end = sOff[w + 1];
    const int blkBeg = sOff[0], blkEnd = sOff[NPB];
    float a[KK];
    #pragma unroll
    for (int k = 0; k < KK; ++k) a[k] = 0.f;

    for (int base = blkBeg; base < blkEnd; base += TC) {
        const int cnt = min(TC, blkEnd - base);
        __syncthreads();   // previous tranche's LDS fully consumed
        {
            const int e    = t & 255;     // edge slot within tranche
            const int half = t >> 8;      // 0: k[0,12)+ch[0,16); 1: k[12,24)+ch[16,32)
            if (e < cnt) {
                const int slot = base + e;
                int g = 0;
                #pragma unroll
                for (int j = 1; j < NPB; ++j) g += (slot >= sOff[j]);
                const int src = srcPerm[slot];
                // ---- delta (duplicated across halves) ----
                float px = pos[src*3+0], py = pos[src*3+1], pz = pos[src*3+2];
                float o0 = ori[src*9+0], o1 = ori[src*9+1], o2 = ori[src*9+2];
                int sqs = seq[src];
                float dx = px - sNd[g][0], dy = py - sNd[g][1], dz = pz - sNd[g][2];
                float dist = sqrtf(dx*dx + dy*dy + dz*dz);
                float inv = 1.f / (dist + 1e-9f);
                float ux = dx*inv, uy = dy*inv, uz = dz*inv;
                float df[7];
                #pragma unroll
                for (int r = 0; r < 3; ++r) {
                    float m0 = sNd[g][3 + r*3 + 0];
                    float m1 = sNd[g][3 + r*3 + 1];
                    float m2 = sNd[g][3 + r*3 + 2];
                    df[r]     = m0*ux + m1*uy + m2*uz;
                    df[3 + r] = m0*o0 + m1*o1 + m2*o2;
                }
                df[6] = dist * 0.125f;
                int dsq = sqs - __float_as_int(sNd[g][12]);
                dsq = dsq < -SS ? -SS : (dsq > SS ? SS : dsq);
                const int sb = dsq + SS;
                // ---- WeightNet: my 12 k's ----
                float wv[12];
                {
                    const float* wb = &sWnb[sb * WBS + half * 12];
                    #pragma unroll
                    for (int j = 0; j < 12; ++j) wv[j] = wb[j];
                }
                const float* wn = &sWnw[sb * WNS + half * 12];
                #pragma unroll
                for (int f = 0; f < 7; ++f) {
                    float d_ = df[f];
                    #pragma unroll
                    for (int j = 0; j < 12; ++j)
                        wv[j] += d_ * wn[f * 24 + j];
                }
                #pragma unroll
                for (int j = 0; j < 12; ++j) wv[j] = wv[j] >= 0.f ? wv[j] : 0.2f * wv[j];
                #pragma unroll
                for (int jj = 0; jj < 6; ++jj)
                    U.stg.w[e * 12 + half * 6 + jj] = bf16pair(wv[2*jj], wv[2*jj+1]);
                // ---- h: my 16 channels ----
                const float4* hs = (const float4*)(hpre + (size_t)src * C_W);
                uint2* hd = (uint2*)&U.stg.h[e * HS + half * 16];
                #pragma unroll
                for (int q = 0; q < 2; ++q) {
                    float4 v0 = hs[half * 4 + 2*q], v1 = hs[half * 4 + 2*q + 1];
                    float f[8] = {v0.x, v0.y, v0.z, v0.w, v1.x, v1.y, v1.z, v1.w};
                    #pragma unroll
                    for (int j = 0; j < 8; ++j) {
                        int ch = half * 16 + q * 8 + j;
                        float av = sA2[ch] * f[j] + sB2[ch];
                        f[j] = av >= 0.f ? av : 0.1f * av;
                    }
                    uint2 p0; p0.x = bf16pair(f[0], f[1]); p0.y = bf16pair(f[2], f[3]);
                    uint2 p1; p1.x = bf16pair(f[4], f[5]); p1.y = bf16pair(f[6], f[7]);
                    hd[2*q] = p0; hd[2*q+1] = p1;
                }
            }
        }
        __syncthreads();
        // ---- phase B: per-wave LDS-only accumulate ----
        const int lo = max(beg, base), hi = min(end, base + cnt);
        #pragma unroll 2
        for (int p = lo + s; p < hi; p += 2) {
            const int pr = p - base;
            const float v = BF_LO((unsigned int)U.stg.h[pr * HS + c]);
            const uint4* wp = (const uint4*)&U.stg.w[pr * 12];
            const uint4 A = wp[0], B = wp[1], Cc = wp[2];
            a[0]  += BF_LO(A.x) * v;  a[1]  += BF_HI(A.x) * v;
            a[2]  += BF_LO(A.y) * v;  a[3]  += BF_HI(A.y) * v;
            a[4]  += BF_LO(A.z) * v;  a[5]  += BF_HI(A.z) * v;
            a[6]  += BF_LO(A.w) * v;  a[7]  += BF_HI(A.w) * v;
            a[8]  += BF_LO(B.x) * v;  a[9]  += BF_HI(B.x) * v;
            a[10] += BF_LO(B.y) * v;  a[11] += BF_HI(B.y) * v;
            a[12] += BF_LO(B.z) * v;  a[13] += BF_HI(B.z) * v;
            a[14] += BF_LO(B.w) * v;  a[15] += BF_HI(B.w) * v;
            a[16] += BF_LO(Cc.x) * v; a[17] += BF_HI(Cc.x) * v;
            a[18] += BF_LO(Cc.y) * v; a[19] += BF_HI(Cc.y) * v;
            a[20] += BF_LO(Cc.z) * v; a[21] += BF_HI(Cc.z) * v;
            a[22] += BF_LO(Cc.w) * v; a[23] += BF_HI(Cc.w) * v;
        }
    }
    __syncthreads();   // staging dead; safe to overlay fin
    #pragma unroll
    for (int k = 0; k < KK; ++k) a[k] += __shfl_xor(a[k], 32, 64);
    if (s == 0) {
        #pragma unroll
        for (int k = 0; k < KK; ++k) U.fin.agg[w][k * C_W + c] = a[k];
    }
    __syncthreads();

    // projection: t = sl(8)*64 + gp(8)*8 + coq(8); 96 rows x 4 cols each
    {
        const int coq = t & 7;
        const int gp  = (t >> 3) & 7;
        const int sl  = t >> 6;
        const int r0  = sl * 96;
        float4 acc; acc.x = acc.y = acc.z = acc.w = 0.f;
        #pragma unroll 6
        for (int rc = 0; rc < 96; rc += 4) {
            const float4 s4 = *(const float4*)&U.fin.agg[gp][r0 + rc];
            const float4 w0 = *(const float4*)&convw[(size_t)(r0+rc+0)*32 + coq*4];
            const float4 w1 = *(const float4*)&convw[(size_t)(r0+rc+1)*32 + coq*4];
            const float4 w2 = *(const float4*)&convw[(size_t)(r0+rc+2)*32 + coq*4];
            const float4 w3 = *(const float4*)&convw[(size_t)(r0+rc+3)*32 + coq*4];
            acc.x += s4.x*w0.x + s4.y*w1.x + s4.z*w2.x + s4.w*w3.x;
            acc.y += s4.x*w0.y + s4.y*w1.y + s4.z*w2.y + s4.w*w3.y;
            acc.z += s4.x*w0.z + s4.y*w1.z + s4.z*w2.z + s4.w*w3.z;
            acc.w += s4.x*w0.w + s4.y*w1.w + s4.z*w2.w + s4.w*w3.w;
        }
        *(float4*)&U.fin.red[sl][gp][coq * 4] = acc;
    }
    __syncthreads();
    if (t < 256) {
        const int gg = t >> 5, co = t & 31;
        float v = 0.f;
        #pragma unroll
        for (int sl = 0; sl < 8; ++sl) v += U.fin.red[sl][gg][co];
        convout[(size_t)(i0 + gg) * C_W + co] = v;
        U.fin.rv[gg][co] = v; U.fin.rq[gg][co] = v * v;
    }
    __syncthreads();
    if (t < 64) {
        int cc = t & 31;
        bool isq = t >= C_W;
        float s2 = 0.f;
        #pragma unroll
        for (int gg = 0; gg < NPB; ++gg)
            s2 += isq ? U.fin.rq[gg][cc] : U.fin.rv[gg][cc];
        atomicAdd(&s3sh[(blockIdx.x & 7) * 64 + t], s2);
    }
}

// ---------------- output: lrelu(bn3(conv)) @ lin2_w + x (float4) ----------------
__global__ void __launch_bounds__(256) k_out(
        const float* __restrict__ conv, const float* __restrict__ s3sh,
        const float* __restrict__ g3, const float* __restrict__ b3,
        const float* __restrict__ w2, const float* __restrict__ x,
        float* __restrict__ out) {
    __shared__ float sAB[2][C_W];
    __shared__ float sh[8][C_W];
    __shared__ float sw2[C_W][C_IN];
    const int t = threadIdx.x;
    const int row0 = blockIdx.x * 8;
    if (t < C_W) {
        float s = 0.f, sq = 0.f;
        #pragma unroll
        for (int j = 0; j < 8; ++j) {
            s  += s3sh[j * 64 + t];
            sq += s3sh[j * 64 + C_W + t];
        }
        float mean = s * (1.f / N_NODES);
        float var = sq * (1.f / N_NODES) - mean * mean;
        float a = g3[t] * rsqrtf(var + 1e-5f);
        sAB[0][t] = a; sAB[1][t] = b3[t] - mean * a;
    }
    for (int idx = t; idx < C_W * C_IN; idx += 256)
        sw2[idx >> 7][idx & 127] = w2[idx];
    __syncthreads();
    {
        float v = conv[(size_t)row0 * C_W + t];
        int r = t >> 5, cc = t & 31;
        v = sAB[0][cc] * v + sAB[1][cc];
        sh[r][cc] = v >= 0.f ? v : 0.1f * v;
    }
    __syncthreads();
    const int r = t >> 5, c4 = (t & 31) * 4;
    float4 acc = *(const float4*)&x[(size_t)(row0 + r) * C_IN + c4];
    #pragma unroll 8
    for (int cw = 0; cw < C_W; ++cw) {
        float hv = sh[r][cw];
        float4 wv = *(const float4*)&sw2[cw][c4];
        acc.x += hv * wv.x; acc.y += hv * wv.y;
        acc.z += hv * wv.z; acc.w += hv * wv.w;
    }
    *(float4*)&out[(size_t)(row0 + r) * C_IN + c4] = acc;
}

extern "C" void kernel_launch(void* const* d_in, const int* in_sizes, int n_in,
                              void* d_out, int out_size, void* d_ws, size_t ws_size,
                              hipStream_t stream) {
    const float* x     = (const float*)d_in[0];
    const float* pos   = (const float*)d_in[1];
    const float* ori   = (const float*)d_in[2];
    const int*   seq   = (const int*)d_in[3];
    const int*   ei    = (const int*)d_in[4];
    const float* bn1g  = (const float*)d_in[5];
    const float* bn1b  = (const float*)d_in[6];
    const float* lin1w = (const float*)d_in[7];
    const float* bn2g  = (const float*)d_in[8];
    const float* bn2b  = (const float*)d_in[9];
    const float* wnw   = (const float*)d_in[10];
    const float* wnb   = (const float*)d_in[11];
    const float* convw = (const float*)d_in[12];
    const float* bn3g  = (const float*)d_in[13];
    const float* bn3b  = (const float*)d_in[14];
    const float* lin2w = (const float*)d_in[15];
    float* out = (float*)d_out;
    const int E = in_sizes[4] / 2;

    char* wsb = (char*)d_ws;
    size_t off = 0;
    auto alloc = [&](size_t bytes) {
        void* p = wsb + off;
        off = (off + bytes + 255) & ~(size_t)255;
        return p;
    };
    float* s1      = (float*)alloc(256 * 4);
    float* s2sh    = (float*)alloc(512 * 4);
    float* s3sh    = (float*)alloc(512 * 4);
    int*   counts  = (int*)alloc((size_t)N_NODES * 4);
    size_t zero_bytes = off;
    int*   offsets = (int*)alloc(((size_t)N_NODES + 1) * 4);
    int*   cursor  = (int*)alloc((size_t)N_NODES * 4);
    int*   srcPerm = (int*)alloc((size_t)E * 4);
    float* hpre    = (float*)alloc((size_t)N_NODES * C_W * 4);
    float* convo   = (float*)alloc((size_t)N_NODES * C_W * 4);

    hipMemsetAsync(wsb, 0, zero_bytes, stream);

    k_pre<<<512, 256, 0, stream>>>(x, s1, ei, E, counts);
    k_scan<<<1, 1024, 0, stream>>>(counts, offsets, cursor);
    k_scatter<<<(E + 255) / 256, 256, 0, stream>>>(ei, E, cursor, srcPerm);
    k_mlp1<<<N_NODES / 32, 256, 0, stream>>>(x, s1, bn1g, bn1b, lin1w, hpre, s2sh);
    k_mega<<<N_NODES / NPB, 512, 0, stream>>>(offsets, srcPerm, pos, ori, seq,
                                              hpre, s2sh, bn2g, bn2b, wnw, wnb,
                                              convw, convo, s3sh);
    k_out<<<N_NODES / 8, 256, 0, stream>>>(convo, s3sh, bn3g, bn3b, lin2w, x, out);
}